// Round 1
// baseline (31456.046 us; speedup 1.0000x reference)
//
#include <hip/hip_runtime.h>
#include <hip/hip_bf16.h>

#define SEQ  192
#define D_IN 156
#define HE   1024
#define HD   512
#define ZD   300
#define NB   64

// ---- ws layout (float indices into (float*)d_ws). Indices 0..1023 are barrier ints. ----
#define OFF_XT  1024                         // xT [192][156][64]  (x transposed per t)
#define OFF_HF  (OFF_XT + SEQ*D_IN*NB)       // enc fwd h ping-pong [2][1024][64]
#define OFF_HB  (OFF_HF + 2*HE*NB)           // enc bwd h ping-pong
#define OFF_CF  (OFF_HB + 2*HE*NB)           // c_f final [64][1024]
#define OFF_CB  (OFF_CF + NB*HE)             // c_b final
#define OFF_H1  (OFF_CB + NB*HE)             // dec h1 ping-pong [2][512][64]
#define OFF_H2  (OFF_H1 + 2*HD*NB)           // dec h2 ping-pong
#define OFF_OT  (OFF_H2 + 2*HD*NB)           // outT [156][64]
// total ~2.46M floats (~9.9 MB)

#define OUT_ZMU  (NB*SEQ*D_IN)
#define OUT_ZVAR (OUT_ZMU + NB*ZD)

// ---------------- threefry2x32 (JAX-compatible, 20 rounds) ----------------
__host__ __device__ inline void threefry2x32(unsigned k0, unsigned k1,
                                             unsigned x0, unsigned x1,
                                             unsigned* o0, unsigned* o1) {
  unsigned ks0 = k0, ks1 = k1, ks2 = 0x1BD11BDAu ^ k0 ^ k1;
  x0 += ks0; x1 += ks1;
#define TF_RND(r) { x0 += x1; x1 = (x1 << (r)) | (x1 >> (32 - (r))); x1 ^= x0; }
  TF_RND(13) TF_RND(15) TF_RND(26) TF_RND(6)
  x0 += ks1; x1 += ks2 + 1u;
  TF_RND(17) TF_RND(29) TF_RND(16) TF_RND(24)
  x0 += ks2; x1 += ks0 + 2u;
  TF_RND(13) TF_RND(15) TF_RND(26) TF_RND(6)
  x0 += ks0; x1 += ks1 + 3u;
  TF_RND(17) TF_RND(29) TF_RND(16) TF_RND(24)
  x0 += ks1; x1 += ks2 + 4u;
  TF_RND(13) TF_RND(15) TF_RND(26) TF_RND(6)
  x0 += ks2; x1 += ks0 + 5u;
#undef TF_RND
  *o0 = x0; *o1 = x1;
}

// partitionable-mode 32-bit random bits for element at linear index idx:
// bits = o0 ^ o1 of block(key, (0, idx)); uniform = bitcast(0x3f800000|bits>>9)-1
__device__ __forceinline__ float tf_mask(unsigned k0, unsigned k1, unsigned idx,
                                         float keep, float scale) {
  unsigned o0, o1;
  threefry2x32(k0, k1, 0u, idx, &o0, &o1);
  unsigned bits = o0 ^ o1;
  float u = __uint_as_float(0x3f800000u | (bits >> 9)) - 1.0f;
  return (u < keep) ? scale : 0.0f;
}

__device__ __forceinline__ float sigf(float x) { return 1.0f / (1.0f + expf(-x)); }

// ---------------- device-wide barrier (grid must be co-resident) ----------------
// Single-use counter per barrier slot (zeroed by hipMemsetAsync each launch).
// Release(agent) on arrive (flushes this XCD's dirty L2 to LLC); relaxed spin;
// one acquire(agent) fence (wave0) before anyone loads cross-WG data.
__device__ __forceinline__ void gbar(int* bar, int idx, int nwg) {
  __syncthreads();
  if (threadIdx.x == 0) {
    __hip_atomic_fetch_add(&bar[idx], 1, __ATOMIC_RELEASE, __HIP_MEMORY_SCOPE_AGENT);
    while (__hip_atomic_load(&bar[idx], __ATOMIC_RELAXED, __HIP_MEMORY_SCOPE_AGENT) < nwg)
      __builtin_amdgcn_s_sleep(2);
  }
  __syncthreads();
  if (threadIdx.x < 64) __builtin_amdgcn_fence(__ATOMIC_ACQUIRE, "agent");
  __syncthreads();
}

// ---------------- xT prep: xT[t][d][b] = x[b][t][d] ----------------
__global__ __launch_bounds__(256) void xt_kernel(const float* __restrict__ x, float* ws) {
  const int t = blockIdx.x;
  float* xT = ws + OFF_XT + (size_t)t * (D_IN * NB);
  __shared__ float sm[D_IN * NB];
  for (int i = threadIdx.x; i < D_IN * NB; i += 256) {
    int b = i / D_IN, d = i - b * D_IN;
    sm[d * NB + b] = x[((size_t)b * SEQ + t) * D_IN + d];
  }
  __syncthreads();
  for (int i = threadIdx.x; i < D_IN * NB; i += 256) xT[i] = sm[i];
}

// ---------------- encoder: 256 WGs x 1024 thr; WG = (dir, 8 hidden dims) ----------------
__global__ __launch_bounds__(1024) void enc_kernel(
    const float* __restrict__ WihF, const float* __restrict__ WhhF,
    const float* __restrict__ bihF, const float* __restrict__ bhhF,
    const float* __restrict__ WihB, const float* __restrict__ WhhB,
    const float* __restrict__ bihB, const float* __restrict__ bhhB,
    float* ws, int* bar) {
  const int wg  = blockIdx.x;
  const int dir = wg >> 7;
  const int j0  = (wg & 127) * 8;
  const float* Wih = dir ? WihB : WihF;
  const float* Whh = dir ? WhhB : WhhF;
  const float* bih = dir ? bihB : bihF;
  const float* bhh = dir ? bhhB : bhhF;
  float* hT = ws + (dir ? OFF_HB : OFF_HF);
  float* cS = ws + (dir ? OFF_CB : OFF_CF);
  const float* xT = ws + OFF_XT;

  const int tid = threadIdx.x;
  const int kh  = tid >> 9;          // K-split half
  const int rl  = (tid >> 4) & 31;   // gate-row within WG (gate*8 + jj)
  const int b0  = (tid & 15) * 4;
  const int gate = rl >> 3, jj = rl & 7;
  const int grow = gate * HE + j0 + jj;
  const float* WhhR = Whh + (size_t)grow * HE;
  const float* WihR = Wih + (size_t)grow * D_IN;

  __shared__ float gsum[2][32][64];
  __shared__ float sbias[32];
  if (tid < 32) {
    int g2 = tid >> 3, j2 = tid & 7;
    int gr = g2 * HE + j0 + j2;
    sbias[tid] = bih[gr] + bhh[gr];
  }
  const int jf = tid >> 6;  // finisher dim (tid<512)
  const int bf = tid & 63;
  float c_state = 0.0f;
  __syncthreads();

  for (int t = 0; t < SEQ; ++t) {
    const int ts = dir ? (SEQ - 1 - t) : t;
    const float* xTt = xT + (size_t)ts * (D_IN * NB);
    const float* hp  = hT + (t & 1) * (HE * NB);
    float a0 = 0.f, a1 = 0.f, a2 = 0.f, a3 = 0.f;
    if (kh == 0) {
#pragma unroll 4
      for (int d = 0; d < D_IN; ++d) {
        float w = WihR[d];
        const float4 v = *(const float4*)(xTt + d * NB + b0);
        a0 += w * v.x; a1 += w * v.y; a2 += w * v.z; a3 += w * v.w;
      }
    }
    if (t > 0) {
      const int kb = kh ? 448 : 0, ke = kh ? 1024 : 448;
#pragma unroll 4
      for (int k = kb; k < ke; ++k) {
        float w = WhhR[k];
        const float4 v = *(const float4*)(hp + k * NB + b0);
        a0 += w * v.x; a1 += w * v.y; a2 += w * v.z; a3 += w * v.w;
      }
    }
    float4 av; av.x = a0; av.y = a1; av.z = a2; av.w = a3;
    *(float4*)&gsum[kh][rl][b0] = av;
    __syncthreads();
    if (tid < 512) {
      float gi = gsum[0][jf     ][bf] + gsum[1][jf     ][bf] + sbias[jf];
      float gf = gsum[0][8  + jf][bf] + gsum[1][8  + jf][bf] + sbias[8 + jf];
      float gg = gsum[0][16 + jf][bf] + gsum[1][16 + jf][bf] + sbias[16 + jf];
      float go = gsum[0][24 + jf][bf] + gsum[1][24 + jf][bf] + sbias[24 + jf];
      float ci = (t == 0) ? 0.0f : c_state;
      float c  = sigf(gf) * ci + sigf(gi) * tanhf(gg);
      float h  = sigf(go) * tanhf(c);
      c_state = c;
      hT[((t + 1) & 1) * (HE * NB) + (j0 + jf) * NB + bf] = h;
      if (t == SEQ - 1) cS[bf * HE + j0 + jf] = c;
    }
    gbar(bar, t, 256);
  }
}

// ---------------- z head: final interleave + enc_m + two [64,2048]x[2048,300] ----------------
__global__ __launch_bounds__(256) void z_kernel(
    const float* __restrict__ Wmu, const float* __restrict__ bmu,
    const float* __restrict__ Wvar, const float* __restrict__ bvar,
    const float* ws, float* __restrict__ dout, unsigned ek0, unsigned ek1) {
  const int r = blockIdx.x;  // 0..63  (torch .view interleave of [2,B,H])
  const int tid = threadIdx.x;
  __shared__ float fin[2 * HE];
  const float* cf = ws + OFF_CF;
  const float* cb = ws + OFF_CB;
  const float K7 = 0.7f, S7 = 1.0f / 0.7f;
  for (int q = tid; q < 2 * HE; q += 256) {
    int half = q >> 10, col = q & 1023;
    float cv = (r < 32) ? cf[(2 * r + half) * HE + col]
                        : cb[(2 * (r - 32) + half) * HE + col];
    fin[q] = cv * tf_mask(ek0, ek1, (unsigned)(r * 2048 + q), K7, S7);
  }
  __syncthreads();
  for (int z = tid; z < ZD; z += 256) {
    const float* wm = Wmu + (size_t)z * (2 * HE);
    const float* wv = Wvar + (size_t)z * (2 * HE);
    float am = 0.f, av = 0.f;
#pragma unroll 4
    for (int q = 0; q < 2 * HE; ++q) { float f = fin[q]; am += f * wm[q]; av += f * wv[q]; }
    dout[OUT_ZMU + r * ZD + z]  = am + bmu[z];
    dout[OUT_ZVAR + r * ZD + z] = av + bvar[z];
  }
}

// ---------------- decoder: 256 WGs x 512 thr; WG = 2 hidden dims of each cell ----------------
__global__ __launch_bounds__(512) void dec_kernel(
    const float* __restrict__ Wih1, const float* __restrict__ Whh1,
    const float* __restrict__ bih1, const float* __restrict__ bhh1,
    const float* __restrict__ Wih2, const float* __restrict__ Whh2,
    const float* __restrict__ bih2, const float* __restrict__ bhh2,
    const float* __restrict__ Wout, const float* __restrict__ bout,
    const float* __restrict__ blc,
    float* ws, int* bar, float* __restrict__ dout,
    unsigned mk1a, unsigned mk1b, unsigned mk2a, unsigned mk2b) {
  const int wg  = blockIdx.x;   // 0..255
  const int tid = threadIdx.x;  // 0..511
  const int kh  = tid >> 7;     // 0..3 K-split
  const int rl  = (tid >> 4) & 7;  // gate*2 + jj
  const int b0  = (tid & 15) * 4;
  const int gate = rl >> 1, jj1 = rl & 1;
  const int grow = gate * HD + 2 * wg + jj1;
  const float* W1x = Wih1 + (size_t)grow * D_IN;
  const float* W1h = Whh1 + (size_t)grow * HD;
  const float* W2x = Wih2 + (size_t)grow * HD;
  const float* W2h = Whh2 + (size_t)grow * HD;
  const float* xT = ws + OFF_XT;
  float* h1T = ws + OFF_H1;
  float* h2T = ws + OFF_H2;
  float* oT  = ws + OFF_OT;

  __shared__ float gsum[4][8][64];
  __shared__ float cred[8][64];
  __shared__ float sb1[8], sb2[8];
  if (tid < 8) {
    int g2 = tid >> 1, j2 = tid & 1;
    int gr = g2 * HD + 2 * wg + j2;
    sb1[tid] = bih1[gr] + bhh1[gr];
    sb2[tid] = bih2[gr] + bhh2[gr];
  }
  float rs1 = 0.0f;  // ones @ W_ih1.T row-sum for t==0 start token
  if (kh == 0) { for (int d = 0; d < D_IN; ++d) rs1 += W1x[d]; }
  const int jf = tid >> 6;  // finisher (tid<128): jf 0..1, bf 0..63
  const int bf = tid & 63;
  const int jcol = 2 * wg + (jf & 1);
  float c1 = 0.0f, c2 = 0.0f;
  float blcv = (tid < 128) ? blc[jcol] : 0.0f;  // context == b_lc (conductor is dead code)
  __syncthreads();

  for (int t = 0; t < SEQ; ++t) {
    const bool up = ((t & 7) == 0) && (t > 0);  // scheduled sampling
    // ---- phase A: cell1 gates ----
    {
      float a0 = 0.f, a1 = 0.f, a2 = 0.f, a3 = 0.f;
      if (t == 0) {
        if (kh == 0) { a0 = a1 = a2 = a3 = rs1; }
      } else {
        const float* src = up ? oT : (xT + (size_t)(t - 1) * (D_IN * NB));
        const int db = kh * 39, de = db + 39;
#pragma unroll 4
        for (int d = db; d < de; ++d) {
          float w = W1x[d];
          const float4 v = *(const float4*)(src + d * NB + b0);
          a0 += w * v.x; a1 += w * v.y; a2 += w * v.z; a3 += w * v.w;
        }
        const float* h1p = h1T + (t & 1) * (HD * NB);
        const int kb = kh * 128, ke = kb + 128;
#pragma unroll 4
        for (int k = kb; k < ke; ++k) {
          float w = W1h[k];
          const float4 v = *(const float4*)(h1p + k * NB + b0);
          a0 += w * v.x; a1 += w * v.y; a2 += w * v.z; a3 += w * v.w;
        }
      }
      float4 av; av.x = a0; av.y = a1; av.z = a2; av.w = a3;
      *(float4*)&gsum[kh][rl][b0] = av;
    }
    __syncthreads();
    if (tid < 128) {
#define SUM4(row) (gsum[0][row][bf] + gsum[1][row][bf] + gsum[2][row][bf] + gsum[3][row][bf])
      float gi = SUM4(0 + jf) + sb1[0 + jf];
      float gf = SUM4(2 + jf) + sb1[2 + jf];
      float gg = SUM4(4 + jf) + sb1[4 + jf];
      float go = SUM4(6 + jf) + sb1[6 + jf];
      float cin = (t > 0 && (t & 31) == 0) ? c1 : blcv;  // reset_c = (t==0)|(t%32!=0)
      float c = sigf(gf) * cin + sigf(gi) * tanhf(gg);
      float h = sigf(go) * tanhf(c);
      c1 = c;
      unsigned i1 = (unsigned)((t * NB + bf) * HD + jcol);
      h *= tf_mask(mk1a, mk1b, i1, 0.5f, 2.0f);  // inplace dropout p=0.5
      h1T[((t + 1) & 1) * (HD * NB) + jcol * NB + bf] = h;
    }
    gbar(bar, 192 + 3 * t, 256);
    // ---- phase B: cell2 gates ----
    {
      float a0 = 0.f, a1 = 0.f, a2 = 0.f, a3 = 0.f;
      if (kh < 2) {
        const float* h1n = h1T + ((t + 1) & 1) * (HD * NB);
        const int kb = kh * 256, ke = kb + 256;
#pragma unroll 4
        for (int k = kb; k < ke; ++k) {
          float w = W2x[k];
          const float4 v = *(const float4*)(h1n + k * NB + b0);
          a0 += w * v.x; a1 += w * v.y; a2 += w * v.z; a3 += w * v.w;
        }
      } else if (t > 0) {
        const float* h2p = h2T + (t & 1) * (HD * NB);
        const int kb = (kh - 2) * 256, ke = kb + 256;
#pragma unroll 4
        for (int k = kb; k < ke; ++k) {
          float w = W2h[k];
          const float4 v = *(const float4*)(h2p + k * NB + b0);
          a0 += w * v.x; a1 += w * v.y; a2 += w * v.z; a3 += w * v.w;
        }
      }
      float4 av; av.x = a0; av.y = a1; av.z = a2; av.w = a3;
      *(float4*)&gsum[kh][rl][b0] = av;
    }
    __syncthreads();
    if (tid < 128) {
      float gi = SUM4(0 + jf) + sb2[0 + jf];
      float gf = SUM4(2 + jf) + sb2[2 + jf];
      float gg = SUM4(4 + jf) + sb2[4 + jf];
      float go = SUM4(6 + jf) + sb2[6 + jf];
      float c = sigf(gf) * c2 + sigf(gi) * tanhf(gg);
      float h = sigf(go) * tanhf(c);
      c2 = c;
      unsigned i2 = (unsigned)((t * NB + bf) * HD + jcol);
      h *= tf_mask(mk2a, mk2b, i2, 0.8f, 1.0f / 0.8f);  // p=0.2
      h2T[((t + 1) & 1) * (HD * NB) + jcol * NB + bf] = h;
#undef SUM4
    }
    gbar(bar, 192 + 3 * t + 1, 256);
    // ---- phase C: out = sigmoid(h2 @ W_out.T + b_out) ----
    if (wg < D_IN) {
      const float* h2n = h2T + ((t + 1) & 1) * (HD * NB);
      const float* wo = Wout + (size_t)wg * HD;
      const int kq = tid >> 6;  // 0..7
      float p = 0.0f;
      for (int k = kq * 64; k < kq * 64 + 64; ++k) p += wo[k] * h2n[k * NB + bf];
      cred[kq][bf] = p;
      __syncthreads();
      if (tid < 64) {
        float o = bout[wg];
#pragma unroll
        for (int q = 0; q < 8; ++q) o += cred[q][tid];
        float val = 1.0f / (1.0f + expf(-o));
        dout[(size_t)tid * (SEQ * D_IN) + t * D_IN + wg] = val;
        oT[wg * NB + tid] = val;  // transposed copy for scheduled-sampling reads
      }
    }
    if (((t + 1) & 7) == 0 && (t + 1) < SEQ) gbar(bar, 192 + 3 * t + 2, 256);
  }
}

extern "C" void kernel_launch(void* const* d_in, const int* in_sizes, int n_in,
                              void* d_out, int out_size, void* d_ws, size_t ws_size,
                              hipStream_t stream) {
  (void)in_sizes; (void)n_in; (void)out_size; (void)ws_size;
  const float* x    = (const float*)d_in[0];
  const float* WihF = (const float*)d_in[1];
  const float* WhhF = (const float*)d_in[2];
  const float* bihF = (const float*)d_in[3];
  const float* bhhF = (const float*)d_in[4];
  const float* WihB = (const float*)d_in[5];
  const float* WhhB = (const float*)d_in[6];
  const float* bihB = (const float*)d_in[7];
  const float* bhhB = (const float*)d_in[8];
  const float* Wmu  = (const float*)d_in[9];
  const float* bmu  = (const float*)d_in[10];
  const float* Wvar = (const float*)d_in[11];
  const float* bvar = (const float*)d_in[12];
  // d_in[13] = W_lc (dead code: relu(0) @ W_lc.T == 0)
  const float* blc  = (const float*)d_in[14];
  const float* Wih1 = (const float*)d_in[15];
  const float* Whh1 = (const float*)d_in[16];
  const float* bih1 = (const float*)d_in[17];
  const float* bhh1 = (const float*)d_in[18];
  const float* Wih2 = (const float*)d_in[19];
  const float* Whh2 = (const float*)d_in[20];
  const float* bih2 = (const float*)d_in[21];
  const float* bhh2 = (const float*)d_in[22];
  const float* Wout = (const float*)d_in[23];
  const float* bout = (const float*)d_in[24];
  float* ws   = (float*)d_ws;
  int*   bar  = (int*)d_ws;  // first 4KB
  float* dout = (float*)d_out;

  // zero the barrier counters (deterministic per launch; graph-capture safe)
  hipMemsetAsync(d_ws, 0, 4096, stream);

  // host-side fold_in(key(42), {0,1,2}); key(42) == (0,42)
  unsigned e0, e1, m10, m11, m20, m21;
  threefry2x32(0u, 42u, 0u, 0u, &e0, &e1);    // enc_m key
  threefry2x32(0u, 42u, 0u, 1u, &m10, &m11);  // m1 key
  threefry2x32(0u, 42u, 0u, 2u, &m20, &m21);  // m2 key

  xt_kernel<<<SEQ, 256, 0, stream>>>(x, ws);
  enc_kernel<<<256, 1024, 0, stream>>>(WihF, WhhF, bihF, bhhF,
                                       WihB, WhhB, bihB, bhhB, ws, bar);
  z_kernel<<<64, 256, 0, stream>>>(Wmu, bmu, Wvar, bvar, ws, dout, e0, e1);
  dec_kernel<<<256, 512, 0, stream>>>(Wih1, Whh1, bih1, bhh1,
                                      Wih2, Whh2, bih2, bhh2,
                                      Wout, bout, blc, ws, bar, dout,
                                      m10, m11, m20, m21);
}

// Round 2
// 7780.236 us; speedup vs baseline: 4.0431x; 4.0431x over previous
//
#include <hip/hip_runtime.h>
#include <hip/hip_bf16.h>

typedef short short8 __attribute__((ext_vector_type(8)));
typedef float f32x4 __attribute__((ext_vector_type(4)));
typedef unsigned short ushort_t;

#define SEQ 192
#define D_IN 156
#define HE 1024
#define HD 512
#define ZD 300
#define NB 64

// ---- ws byte offsets ----
#define XB_OFF   4096                          // bf16 x, padded: [192][64][160]
#define ONES_OFF (XB_OFF + SEQ*NB*160*2)       // bf16 ones row: [64][160]
#define OT_OFF   (ONES_OFF + NB*160*2)         // bf16 prev-out: [64][160]
#define HE_OFF   (OT_OFF + NB*160*2)           // bf16 enc h: [2dir][2pp][64][1024]
#define H1_OFF   (HE_OFF + 2*2*NB*HE*2)        // bf16 dec h1: [2pp][64][512]
#define H2_OFF   (H1_OFF + 2*NB*HD*2)          // bf16 dec h2: [2pp][64][512]
#define CF_OFF   (H2_OFF + 2*NB*HD*2)          // f32 c_f final: [64][1024]
#define CB_OFF   (CF_OFF + NB*HE*4)            // f32 c_b final: [64][1024]

#define OUT_ZMU  (NB*SEQ*D_IN)
#define OUT_ZVAR (OUT_ZMU + NB*ZD)

// ---------------- threefry2x32 (JAX-compatible, 20 rounds) ----------------
__host__ __device__ inline void threefry2x32(unsigned k0, unsigned k1,
                                             unsigned x0, unsigned x1,
                                             unsigned* o0, unsigned* o1) {
  unsigned ks0 = k0, ks1 = k1, ks2 = 0x1BD11BDAu ^ k0 ^ k1;
  x0 += ks0; x1 += ks1;
#define TF_RND(r) { x0 += x1; x1 = (x1 << (r)) | (x1 >> (32 - (r))); x1 ^= x0; }
  TF_RND(13) TF_RND(15) TF_RND(26) TF_RND(6)
  x0 += ks1; x1 += ks2 + 1u;
  TF_RND(17) TF_RND(29) TF_RND(16) TF_RND(24)
  x0 += ks2; x1 += ks0 + 2u;
  TF_RND(13) TF_RND(15) TF_RND(26) TF_RND(6)
  x0 += ks0; x1 += ks1 + 3u;
  TF_RND(17) TF_RND(29) TF_RND(16) TF_RND(24)
  x0 += ks1; x1 += ks2 + 4u;
  TF_RND(13) TF_RND(15) TF_RND(26) TF_RND(6)
  x0 += ks2; x1 += ks0 + 5u;
#undef TF_RND
  *o0 = x0; *o1 = x1;
}

__device__ __forceinline__ float tf_mask(unsigned k0, unsigned k1, unsigned idx,
                                         float keep, float scale) {
  unsigned o0, o1;
  threefry2x32(k0, k1, 0u, idx, &o0, &o1);
  unsigned bits = o0 ^ o1;
  float u = __uint_as_float(0x3f800000u | (bits >> 9)) - 1.0f;
  return (u < keep) ? scale : 0.0f;
}

__device__ __forceinline__ float sigf(float x) { return 1.0f / (1.0f + expf(-x)); }

__device__ __forceinline__ ushort_t f2bf(float f) {  // RNE float->bf16
  unsigned u = __float_as_uint(f);
  return (ushort_t)((u + 0x7fffu + ((u >> 16) & 1u)) >> 16);
}

#define MFMA(a,b,c) __builtin_amdgcn_mfma_f32_16x16x32_bf16((a),(b),(c),0,0,0)

// ---------------- device-wide barrier (proven in round 1) ----------------
__device__ __forceinline__ void gbar(int* bar, int idx, int nwg) {
  __syncthreads();
  if (threadIdx.x == 0) {
    __hip_atomic_fetch_add(&bar[idx], 1, __ATOMIC_RELEASE, __HIP_MEMORY_SCOPE_AGENT);
    while (__hip_atomic_load(&bar[idx], __ATOMIC_RELAXED, __HIP_MEMORY_SCOPE_AGENT) < nwg)
      __builtin_amdgcn_s_sleep(2);
  }
  __syncthreads();
  if (threadIdx.x < 64) __builtin_amdgcn_fence(__ATOMIC_ACQUIRE, "agent");
  __syncthreads();
}

// ---------------- prep: x -> bf16 padded [t][b][160]; ones row; oT pad ----------------
__global__ __launch_bounds__(256) void prep_kernel(const float* __restrict__ x, char* wsb) {
  const int t = blockIdx.x;
  ushort_t* xb = (ushort_t*)(wsb + XB_OFF) + (size_t)t * NB * 160;
  for (int i = threadIdx.x; i < NB * 160; i += 256) {
    int b = i / 160, d = i - b * 160;
    xb[i] = (d < D_IN) ? f2bf(x[((size_t)b * SEQ + t) * D_IN + d]) : (ushort_t)0;
  }
  if (t == 0) {
    ushort_t* on = (ushort_t*)(wsb + ONES_OFF);
    ushort_t* oT = (ushort_t*)(wsb + OT_OFF);
    for (int i = threadIdx.x; i < NB * 160; i += 256) {
      int d = i - (i / 160) * 160;
      on[i] = (d < D_IN) ? (ushort_t)0x3F80 : (ushort_t)0;  // bf16 1.0
      oT[i] = 0;
    }
  }
}

// ---------------- encoder: 256 WGs x 512 thr; wave = one 16x16 gate tile ----------------
// WG = (dir, batch-tile bt in 0..3, dim-pair dp in 0..31); wave w: dtL=w>>2, gate=w&3
__global__ __launch_bounds__(512, 2) void enc_kernel(
    const float* __restrict__ WihF, const float* __restrict__ WhhF,
    const float* __restrict__ bihF, const float* __restrict__ bhhF,
    const float* __restrict__ WihB, const float* __restrict__ WhhB,
    const float* __restrict__ bihB, const float* __restrict__ bhhB,
    char* wsb, int* bar) {
  const int wg = blockIdx.x;
  const int dir = wg >> 7;
  const int bt  = (wg >> 5) & 3;
  const int dp  = wg & 31;
  const int tid = threadIdx.x;
  const int w   = tid >> 6;
  const int l   = tid & 63;
  const int dtL = w >> 2, gate = w & 3;
  const int dimbase = dp * 32 + dtL * 16;
  const int wrow = dimbase + (l & 15);
  const int grow = gate * HE + wrow;
  const int kseg = (l >> 4) * 8;

  const float* Whh = dir ? WhhB : WhhF;
  const float* Wih = dir ? WihB : WihF;
  const float* bih = dir ? bihB : bihF;
  const float* bhh = dir ? bhhB : bhhF;

  // weights -> bf16 B-fragments, register-resident (fence-immune)
  short8 wreg[37];
#pragma unroll
  for (int c = 0; c < 32; ++c) {
    const float* p = Whh + (size_t)grow * HE + c * 32 + kseg;
    short8 v;
#pragma unroll
    for (int j = 0; j < 8; ++j) v[j] = (short)f2bf(p[j]);
    wreg[c] = v;
  }
#pragma unroll
  for (int c = 0; c < 5; ++c) {
    short8 v;
#pragma unroll
    for (int j = 0; j < 8; ++j) {
      int k = c * 32 + kseg + j;
      v[j] = (k < D_IN) ? (short)f2bf(Wih[(size_t)grow * D_IN + k]) : (short)0;
    }
    wreg[32 + c] = v;
  }

  const ushort_t* xb = (const ushort_t*)(wsb + XB_OFF);
  ushort_t* hD = (ushort_t*)(wsb + HE_OFF) + (size_t)dir * (2 * NB * HE);
  float* cS = (float*)(wsb + (dir ? CB_OFF : CF_OFF));

  __shared__ float gLDS[8][16][16];
  __shared__ float sbias[4][32];
  if (tid < 128) {
    int g = tid >> 5, dd = tid & 31;
    int gr = g * HE + dp * 32 + dd;
    sbias[g][dd] = bih[gr] + bhh[gr];
  }
  const int fdt = tid >> 8, fb = (tid >> 4) & 15, fd = tid & 15;
  const int fbg = bt * 16 + fb;
  const int fdg = dp * 32 + fdt * 16 + fd;
  const int arow = bt * 16 + (l & 15);
  float cc = 0.f;
  __syncthreads();

  for (int t = 0; t < SEQ; ++t) {
    const int ts = dir ? (SEQ - 1 - t) : t;
    f32x4 acc = {0.f, 0.f, 0.f, 0.f};
    const ushort_t* xp = xb + (size_t)ts * NB * 160 + arow * 160 + kseg;
#pragma unroll
    for (int c = 0; c < 5; ++c)
      acc = MFMA(*(const short8*)(const void*)(xp + c * 32), wreg[32 + c], acc);
    if (t > 0) {
      const ushort_t* hp = hD + (size_t)(t & 1) * NB * HE + arow * HE + kseg;
#pragma unroll
      for (int c = 0; c < 32; ++c)
        acc = MFMA(*(const short8*)(const void*)(hp + c * 32), wreg[c], acc);
    }
#pragma unroll
    for (int r = 0; r < 4; ++r)
      gLDS[w][(l >> 4) * 4 + r][l & 15] = acc[r];
    __syncthreads();
    {  // finisher: all 512 threads = 2 dim-tiles x 16 batch x 16 dim
      float gi = gLDS[fdt * 4 + 0][fb][fd] + sbias[0][fdt * 16 + fd];
      float gf = gLDS[fdt * 4 + 1][fb][fd] + sbias[1][fdt * 16 + fd];
      float gg = gLDS[fdt * 4 + 2][fb][fd] + sbias[2][fdt * 16 + fd];
      float go = gLDS[fdt * 4 + 3][fb][fd] + sbias[3][fdt * 16 + fd];
      float ci = (t == 0) ? 0.f : cc;
      cc = sigf(gf) * ci + sigf(gi) * tanhf(gg);
      float h = sigf(go) * tanhf(cc);
      hD[(size_t)((t + 1) & 1) * NB * HE + (size_t)fbg * HE + fdg] = f2bf(h);
      if (t == SEQ - 1) cS[(size_t)fbg * HE + fdg] = cc;  // fp32 c for z head
    }
    gbar(bar, dir * SEQ + t, 128);  // per-direction barrier
  }
}

// ---------------- z head (unchanged logic; reads fp32 cS) ----------------
__global__ __launch_bounds__(256) void z_kernel(
    const float* __restrict__ Wmu, const float* __restrict__ bmu,
    const float* __restrict__ Wvar, const float* __restrict__ bvar,
    const char* wsb, float* __restrict__ dout, unsigned ek0, unsigned ek1) {
  const int r = blockIdx.x;
  const int tid = threadIdx.x;
  __shared__ float fin[2 * HE];
  const float* cf = (const float*)(wsb + CF_OFF);
  const float* cb = (const float*)(wsb + CB_OFF);
  const float K7 = 0.7f, S7 = 1.0f / 0.7f;
  for (int q = tid; q < 2 * HE; q += 256) {
    int half = q >> 10, col = q & 1023;
    float cv = (r < 32) ? cf[(2 * r + half) * HE + col]
                        : cb[(2 * (r - 32) + half) * HE + col];
    fin[q] = cv * tf_mask(ek0, ek1, (unsigned)(r * 2048 + q), K7, S7);
  }
  __syncthreads();
  for (int z = tid; z < ZD; z += 256) {
    const float* wm = Wmu + (size_t)z * (2 * HE);
    const float* wv = Wvar + (size_t)z * (2 * HE);
    float am = 0.f, av = 0.f;
#pragma unroll 4
    for (int q = 0; q < 2 * HE; ++q) { float f = fin[q]; am += f * wm[q]; av += f * wv[q]; }
    dout[OUT_ZMU + r * ZD + z]  = am + bmu[z];
    dout[OUT_ZVAR + r * ZD + z] = av + bvar[z];
  }
}

// ---------------- decoder: 128 WGs x 512 thr ----------------
// WG = (bt in 0..3, dt in 0..31); waves 0-3 = cell1 gates, 4-7 = cell2 gates;
// wave 0 of WGs with dt<10 also owns the W_out tile (bt, ot=dt).
__global__ __launch_bounds__(512, 2) void dec_kernel(
    const float* __restrict__ Wih1, const float* __restrict__ Whh1,
    const float* __restrict__ bih1, const float* __restrict__ bhh1,
    const float* __restrict__ Wih2, const float* __restrict__ Whh2,
    const float* __restrict__ bih2, const float* __restrict__ bhh2,
    const float* __restrict__ Wout, const float* __restrict__ bout,
    const float* __restrict__ blc,
    char* wsb, int* bar, float* __restrict__ dout,
    unsigned mk1a, unsigned mk1b, unsigned mk2a, unsigned mk2b) {
  const int wg = blockIdx.x;
  const int bt = wg >> 5;
  const int dt = wg & 31;
  const int d0 = dt * 16;
  const int tid = threadIdx.x;
  const int w = tid >> 6, l = tid & 63;
  const int kseg = (l >> 4) * 8;
  const bool isC1 = (w < 4);
  const int gate = w & 3;
  const int wrow = d0 + (l & 15);
  const int grow = gate * HD + wrow;
  const bool hasOut = (w == 0) && (dt < 10);
  const int orow = dt * 16 + (l & 15);  // output dim (W_out row)

  short8 wreg[37];  // union-allocated: cell1 uses 0..20 (+21..36 for Wout), cell2 uses 0..31
  if (isC1) {
#pragma unroll
    for (int c = 0; c < 5; ++c) {
      short8 v;
#pragma unroll
      for (int j = 0; j < 8; ++j) {
        int k = c * 32 + kseg + j;
        v[j] = (k < D_IN) ? (short)f2bf(Wih1[(size_t)grow * D_IN + k]) : (short)0;
      }
      wreg[c] = v;
    }
#pragma unroll
    for (int c = 0; c < 16; ++c) {
      const float* p = Whh1 + (size_t)grow * HD + c * 32 + kseg;
      short8 v;
#pragma unroll
      for (int j = 0; j < 8; ++j) v[j] = (short)f2bf(p[j]);
      wreg[5 + c] = v;
    }
    if (hasOut) {
#pragma unroll
      for (int c = 0; c < 16; ++c) {
        short8 v;
        if (orow < D_IN) {
          const float* p = Wout + (size_t)orow * HD + c * 32 + kseg;
#pragma unroll
          for (int j = 0; j < 8; ++j) v[j] = (short)f2bf(p[j]);
        } else {
#pragma unroll
          for (int j = 0; j < 8; ++j) v[j] = 0;
        }
        wreg[21 + c] = v;
      }
    }
  } else {
#pragma unroll
    for (int c = 0; c < 16; ++c) {
      const float* p = Wih2 + (size_t)grow * HD + c * 32 + kseg;
      short8 v;
#pragma unroll
      for (int j = 0; j < 8; ++j) v[j] = (short)f2bf(p[j]);
      wreg[c] = v;
    }
#pragma unroll
    for (int c = 0; c < 16; ++c) {
      const float* p = Whh2 + (size_t)grow * HD + c * 32 + kseg;
      short8 v;
#pragma unroll
      for (int j = 0; j < 8; ++j) v[j] = (short)f2bf(p[j]);
      wreg[16 + c] = v;
    }
  }

  const ushort_t* xb = (const ushort_t*)(wsb + XB_OFF);
  const ushort_t* on = (const ushort_t*)(wsb + ONES_OFF);
  ushort_t* oT  = (ushort_t*)(wsb + OT_OFF);
  ushort_t* h1b = (ushort_t*)(wsb + H1_OFF);
  ushort_t* h2b = (ushort_t*)(wsb + H2_OFF);

  __shared__ float gLDS[8][16][16];
  __shared__ float sb1[4][16], sb2[4][16];
  if (tid < 64) {
    int g = tid >> 4, dd = tid & 15; int gr = g * HD + d0 + dd;
    sb1[g][dd] = bih1[gr] + bhh1[gr];
  } else if (tid < 128) {
    int q = tid - 64; int g = q >> 4, dd = q & 15; int gr = g * HD + d0 + dd;
    sb2[g][dd] = bih2[gr] + bhh2[gr];
  }

  const int fb = (tid >> 4) & 15, fd = tid & 15;
  const int fbg = bt * 16 + fb, fdg = d0 + fd;
  const bool isFin = (tid < 256);
  float c1 = 0.f, c2 = 0.f;
  float blcv = isFin ? blc[fdg] : 0.f;  // context == b_lc (conductor is dead code)
  float bo = (hasOut && orow < D_IN) ? bout[orow] : 0.f;
  const int arow = bt * 16 + (l & 15);
  __syncthreads();

  for (int t = 0; t < SEQ; ++t) {
    const bool up = ((t & 7) == 0) && (t > 0);  // scheduled sampling
    // ---- phase A: cell1 ----
    if (isC1) {
      f32x4 acc = {0.f, 0.f, 0.f, 0.f};
      const ushort_t* src = (t == 0) ? (on + arow * 160 + kseg)
                        : up ? (oT + arow * 160 + kseg)
                             : (xb + (size_t)(t - 1) * NB * 160 + arow * 160 + kseg);
#pragma unroll
      for (int c = 0; c < 5; ++c)
        acc = MFMA(*(const short8*)(const void*)(src + c * 32), wreg[c], acc);
      if (t > 0) {
        const ushort_t* hp = h1b + (size_t)(t & 1) * NB * HD + arow * HD + kseg;
#pragma unroll
        for (int c = 0; c < 16; ++c)
          acc = MFMA(*(const short8*)(const void*)(hp + c * 32), wreg[5 + c], acc);
      }
#pragma unroll
      for (int r = 0; r < 4; ++r)
        gLDS[w][(l >> 4) * 4 + r][l & 15] = acc[r];
    }
    __syncthreads();
    if (isFin) {
      float gi = gLDS[0][fb][fd] + sb1[0][fd];
      float gf = gLDS[1][fb][fd] + sb1[1][fd];
      float gg = gLDS[2][fb][fd] + sb1[2][fd];
      float go = gLDS[3][fb][fd] + sb1[3][fd];
      float cin = (t > 0 && (t & 31) == 0) ? c1 : blcv;  // reset_c=(t==0)|(t%32!=0)
      c1 = sigf(gf) * cin + sigf(gi) * tanhf(gg);
      float h = sigf(go) * tanhf(c1);
      h *= tf_mask(mk1a, mk1b, (unsigned)((t * NB + fbg) * HD + fdg), 0.5f, 2.0f);
      h1b[(size_t)((t + 1) & 1) * NB * HD + (size_t)fbg * HD + fdg] = f2bf(h);
    }
    gbar(bar, 2 * SEQ + 3 * t, 128);
    // ---- phase B: cell2 ----
    if (!isC1) {
      f32x4 acc = {0.f, 0.f, 0.f, 0.f};
      const ushort_t* hp1 = h1b + (size_t)((t + 1) & 1) * NB * HD + arow * HD + kseg;
#pragma unroll
      for (int c = 0; c < 16; ++c)
        acc = MFMA(*(const short8*)(const void*)(hp1 + c * 32), wreg[c], acc);
      if (t > 0) {
        const ushort_t* hp2 = h2b + (size_t)(t & 1) * NB * HD + arow * HD + kseg;
#pragma unroll
        for (int c = 0; c < 16; ++c)
          acc = MFMA(*(const short8*)(const void*)(hp2 + c * 32), wreg[16 + c], acc);
      }
#pragma unroll
      for (int r = 0; r < 4; ++r)
        gLDS[w][(l >> 4) * 4 + r][l & 15] = acc[r];
    }
    __syncthreads();
    if (isFin) {
      float gi = gLDS[4][fb][fd] + sb2[0][fd];
      float gf = gLDS[5][fb][fd] + sb2[1][fd];
      float gg = gLDS[6][fb][fd] + sb2[2][fd];
      float go = gLDS[7][fb][fd] + sb2[3][fd];
      c2 = sigf(gf) * c2 + sigf(gi) * tanhf(gg);
      float h = sigf(go) * tanhf(c2);
      h *= tf_mask(mk2a, mk2b, (unsigned)((t * NB + fbg) * HD + fdg), 0.8f, 1.25f);
      h2b[(size_t)((t + 1) & 1) * NB * HD + (size_t)fbg * HD + fdg] = f2bf(h);
    }
    gbar(bar, 2 * SEQ + 3 * t + 1, 128);
    // ---- phase C: out = sigmoid(h2 @ W_out.T + b_out) ----
    if (hasOut) {
      f32x4 acc = {0.f, 0.f, 0.f, 0.f};
      const ushort_t* hp2 = h2b + (size_t)((t + 1) & 1) * NB * HD + arow * HD + kseg;
#pragma unroll
      for (int c = 0; c < 16; ++c)
        acc = MFMA(*(const short8*)(const void*)(hp2 + c * 32), wreg[21 + c], acc);
      if (orow < D_IN) {
#pragma unroll
        for (int r = 0; r < 4; ++r) {
          int bg = bt * 16 + (l >> 4) * 4 + r;
          float v = sigf(acc[r] + bo);
          dout[(size_t)bg * (SEQ * D_IN) + t * D_IN + orow] = v;
          oT[bg * 160 + orow] = f2bf(v);
        }
      }
    }
    if (((t + 1) & 7) == 0 && (t + 1) < SEQ) gbar(bar, 2 * SEQ + 3 * t + 2, 128);
  }
}

extern "C" void kernel_launch(void* const* d_in, const int* in_sizes, int n_in,
                              void* d_out, int out_size, void* d_ws, size_t ws_size,
                              hipStream_t stream) {
  (void)in_sizes; (void)n_in; (void)out_size; (void)ws_size;
  const float* x    = (const float*)d_in[0];
  const float* WihF = (const float*)d_in[1];
  const float* WhhF = (const float*)d_in[2];
  const float* bihF = (const float*)d_in[3];
  const float* bhhF = (const float*)d_in[4];
  const float* WihB = (const float*)d_in[5];
  const float* WhhB = (const float*)d_in[6];
  const float* bihB = (const float*)d_in[7];
  const float* bhhB = (const float*)d_in[8];
  const float* Wmu  = (const float*)d_in[9];
  const float* bmu  = (const float*)d_in[10];
  const float* Wvar = (const float*)d_in[11];
  const float* bvar = (const float*)d_in[12];
  // d_in[13] = W_lc (dead: relu(0) @ W_lc.T == 0)
  const float* blc  = (const float*)d_in[14];
  const float* Wih1 = (const float*)d_in[15];
  const float* Whh1 = (const float*)d_in[16];
  const float* bih1 = (const float*)d_in[17];
  const float* bhh1 = (const float*)d_in[18];
  const float* Wih2 = (const float*)d_in[19];
  const float* Whh2 = (const float*)d_in[20];
  const float* bih2 = (const float*)d_in[21];
  const float* bhh2 = (const float*)d_in[22];
  const float* Wout = (const float*)d_in[23];
  const float* bout = (const float*)d_in[24];
  char* wsb = (char*)d_ws;
  int*  bar = (int*)d_ws;  // first 4KB = barrier counters
  float* dout = (float*)d_out;

  hipMemsetAsync(d_ws, 0, 4096, stream);

  unsigned e0, e1, m10, m11, m20, m21;
  threefry2x32(0u, 42u, 0u, 0u, &e0, &e1);    // enc_m key
  threefry2x32(0u, 42u, 0u, 1u, &m10, &m11);  // m1 key
  threefry2x32(0u, 42u, 0u, 2u, &m20, &m21);  // m2 key

  prep_kernel<<<SEQ, 256, 0, stream>>>(x, wsb);
  enc_kernel<<<256, 512, 0, stream>>>(WihF, WhhF, bihF, bhhF,
                                      WihB, WhhB, bihB, bhhB, wsb, bar);
  z_kernel<<<64, 256, 0, stream>>>(Wmu, bmu, Wvar, bvar, wsb, dout, e0, e1);
  dec_kernel<<<128, 512, 0, stream>>>(Wih1, Whh1, bih1, bhh1,
                                      Wih2, Whh2, bih2, bhh2,
                                      Wout, bout, blc, wsb, bar, dout,
                                      m10, m11, m20, m21);
}